// Round 1
// baseline (1369.461 us; speedup 1.0000x reference)
//
#include <hip/hip_runtime.h>

// BitMoE: dense 8-expert BitNet MoE, T=4096 tokens, D=1024, H=4096.
// Strategy: quantized activations are exact small ints, weights exact ternary,
// so f16 MFMA with fp32 accumulation computes the integer dot products EXACTLY.
// All quant scales fold into fp32 epilogues.

#define T_TOK 4096
#define DIMS  1024
#define HID   4096
#define NE    8

typedef __attribute__((ext_vector_type(8))) _Float16 f16x8;
typedef __attribute__((ext_vector_type(4))) _Float16 f16x4;
typedef __attribute__((ext_vector_type(4))) float    f32x4;

// ---------- helpers ----------
__device__ __forceinline__ float block_sum(float v, float* buf, int tid) {
  #pragma unroll
  for (int o = 32; o > 0; o >>= 1) v += __shfl_down(v, o, 64);
  __syncthreads();
  if ((tid & 63) == 0) buf[tid >> 6] = v;
  __syncthreads();
  return buf[0] + buf[1] + buf[2] + buf[3];
}
__device__ __forceinline__ float block_max(float v, float* buf, int tid) {
  #pragma unroll
  for (int o = 32; o > 0; o >>= 1) { float t = __shfl_down(v, o, 64); v = fmaxf(v, t); }
  __syncthreads();
  if ((tid & 63) == 0) buf[tid >> 6] = v;
  __syncthreads();
  return fmaxf(fmaxf(buf[0], buf[1]), fmaxf(buf[2], buf[3]));
}

// async global->LDS, 16B per lane; LDS dest = wave-uniform base + lane*16
__device__ __forceinline__ void gl_lds16(const _Float16* g, _Float16* l) {
  __builtin_amdgcn_global_load_lds(
      (const __attribute__((address_space(1))) unsigned int*)g,
      (__attribute__((address_space(3))) unsigned int*)l, 16, 0, 0);
}

// ---------- weight scale reduction: sum |w| per group ----------
__global__ __launch_bounds__(256) void wabs_sum_kernel(
    const float4* __restrict__ w, int n_f4, int shift, float* __restrict__ sums) {
  __shared__ float buf[4];
  const int tid = threadIdx.x;
  const int base = blockIdx.x * 4096;
  float acc = 0.0f;
  for (int k = 0; k < 16; ++k) {
    int fi = base + k * 256 + tid;
    if (fi < n_f4) {
      float4 v = w[fi];
      acc += fabsf(v.x) + fabsf(v.y) + fabsf(v.z) + fabsf(v.w);
    }
  }
  acc = block_sum(acc, buf, tid);
  if (tid == 0) atomicAdd(&sums[base >> shift], acc);
}

// ---------- scales: sabs = max(mean|w|,1e-5), qs = 1/sabs ----------
__global__ void mkscales_kernel(const float* __restrict__ wsum, float* __restrict__ sc) {
  if (threadIdx.x == 0) {
    #pragma unroll
    for (int e = 0; e < NE; ++e) {
      float m1 = fmaxf(wsum[e] * (1.0f / 4194304.0f), 1e-5f);
      sc[e] = m1; sc[8 + e] = 1.0f / m1;
      float m2 = fmaxf(wsum[8 + e] * (1.0f / 4194304.0f), 1e-5f);
      sc[16 + e] = m2; sc[24 + e] = 1.0f / m2;
    }
    float mg = fmaxf(wsum[16] * (1.0f / 8192.0f), 1e-5f);
    sc[32] = mg; sc[33] = 1.0f / mg;
  }
}

// ---------- ternary weight quant -> f16 {-1,0,1} ----------
__global__ __launch_bounds__(256) void wquant_kernel(
    const float4* __restrict__ w, _Float16* __restrict__ o, int n_f4, int shift,
    const float* __restrict__ qs) {
  int fi = blockIdx.x * 256 + threadIdx.x;
  if (fi >= n_f4) return;
  const float s = qs[fi >> shift];
  float4 v = w[fi];
  f16x4 u;
  u[0] = (_Float16)fminf(fmaxf(rintf(v.x * s), -1.0f), 1.0f);
  u[1] = (_Float16)fminf(fmaxf(rintf(v.y * s), -1.0f), 1.0f);
  u[2] = (_Float16)fminf(fmaxf(rintf(v.z * s), -1.0f), 1.0f);
  u[3] = (_Float16)fminf(fmaxf(rintf(v.w * s), -1.0f), 1.0f);
  ((f16x4*)o)[fi] = u;
}

// ---------- token preprocess: rmsnorm + act_quant + gate softmax ----------
__global__ __launch_bounds__(256) void preprocess_kernel(
    const float* __restrict__ x, const float* __restrict__ gw,
    const float* __restrict__ gb, const float* __restrict__ scales,
    _Float16* __restrict__ qx, float* __restrict__ inv_sx, float* __restrict__ gates) {
  __shared__ float buf[4];
  const int t = blockIdx.x, tid = threadIdx.x;
  const float4 xv = ((const float4*)(x + (size_t)t * DIMS))[tid];
  float ss = xv.x * xv.x + xv.y * xv.y + xv.z * xv.z + xv.w * xv.w;
  ss = block_sum(ss, buf, tid);
  const float rr = 32.0f / fmaxf(sqrtf(ss), 1e-12f); // sqrt(1024)=32
  const float y0 = xv.x * rr, y1 = xv.y * rr, y2 = xv.z * rr, y3 = xv.w * rr;
  float am = fmaxf(fmaxf(fabsf(y0), fabsf(y1)), fmaxf(fabsf(y2), fabsf(y3)));
  am = block_max(am, buf, tid);
  const float aclip = fmaxf(am, 1e-5f);
  const float qsc = 127.0f / aclip;
  const float q0 = fminf(fmaxf(rintf(y0 * qsc), -128.0f), 127.0f);
  const float q1 = fminf(fmaxf(rintf(y1 * qsc), -128.0f), 127.0f);
  const float q2 = fminf(fmaxf(rintf(y2 * qsc), -128.0f), 127.0f);
  const float q3 = fminf(fmaxf(rintf(y3 * qsc), -128.0f), 127.0f);
  f16x4 qu; qu[0] = (_Float16)q0; qu[1] = (_Float16)q1; qu[2] = (_Float16)q2; qu[3] = (_Float16)q3;
  ((f16x4*)(qx + (size_t)t * DIMS))[tid] = qu;

  // gate logits: exact integer dots with on-the-fly ternary gw
  const float gsabs = scales[32], gqs = scales[33];
  float lg[NE];
  #pragma unroll
  for (int e = 0; e < NE; ++e) {
    const float4 gv = ((const float4*)(gw + e * DIMS))[tid];
    float t0 = fminf(fmaxf(rintf(gv.x * gqs), -1.0f), 1.0f);
    float t1 = fminf(fmaxf(rintf(gv.y * gqs), -1.0f), 1.0f);
    float t2 = fminf(fmaxf(rintf(gv.z * gqs), -1.0f), 1.0f);
    float t3 = fminf(fmaxf(rintf(gv.w * gqs), -1.0f), 1.0f);
    lg[e] = q0 * t0 + q1 * t1 + q2 * t2 + q3 * t3;
  }
  #pragma unroll
  for (int e = 0; e < NE; ++e) lg[e] = block_sum(lg[e], buf, tid);
  if (tid == 0) {
    const float isx = aclip / 127.0f;
    inv_sx[t] = isx;
    float l[NE], mx = -1e30f;
    #pragma unroll
    for (int e = 0; e < NE; ++e) { l[e] = lg[e] * (isx * gsabs) + gb[e]; mx = fmaxf(mx, l[e]); }
    float s = 0.0f;
    #pragma unroll
    for (int e = 0; e < NE; ++e) { l[e] = expf(l[e] - mx); s += l[e]; }
    const float inv = 1.0f / s;
    #pragma unroll
    for (int e = 0; e < NE; ++e) gates[t * NE + e] = l[e] * inv;
  }
}

// ---------- GEMM1: h = qx(int) . w1q(tern), epilogue scale+bias+GELU -> f16 ----------
__global__ __launch_bounds__(256) void gemm1_kernel(
    const _Float16* __restrict__ qx, const _Float16* __restrict__ w1q,
    const float* __restrict__ scales, const float* __restrict__ inv_sx,
    const float* __restrict__ b1, _Float16* __restrict__ qa,
    unsigned long long qa_zstride, int e0) {
  __shared__ __align__(16) _Float16 sA[128 * 32];
  __shared__ __align__(16) _Float16 sB[128 * 32];
  const int e = e0 + blockIdx.z;
  const _Float16* A = qx;                                  // [T][1024]
  const _Float16* Bm = w1q + (size_t)e * HID * DIMS;       // [H][1024]
  _Float16* outp = qa + (size_t)blockIdx.z * qa_zstride;   // [T][H]
  const int m0 = blockIdx.x * 128, n0 = blockIdx.y * 128;
  const int tid = threadIdx.x, lane = tid & 63, wv = tid >> 6;
  const int wr = (wv >> 1) * 64, wc = (wv & 1) * 64, lm = lane & 15, lq = lane >> 4;
  f32x4 acc[4][4] = {};
  for (int k0 = 0; k0 < DIMS; k0 += 32) {
    #pragma unroll
    for (int is = 0; is < 2; ++is) {
      const int c = is * 256 + tid;
      const int row = c >> 2, kc = (c & 3) * 8;
      gl_lds16(A + (size_t)(m0 + row) * DIMS + k0 + kc, &sA[c * 8]);
      gl_lds16(Bm + (size_t)(n0 + row) * DIMS + k0 + kc, &sB[c * 8]);
    }
    __syncthreads();
    f16x8 av[4], bv[4];
    #pragma unroll
    for (int i = 0; i < 4; ++i) av[i] = *(const f16x8*)&sA[(wr + i * 16 + lm) * 32 + lq * 8];
    #pragma unroll
    for (int j = 0; j < 4; ++j) bv[j] = *(const f16x8*)&sB[(wc + j * 16 + lm) * 32 + lq * 8];
    #pragma unroll
    for (int i = 0; i < 4; ++i)
      #pragma unroll
      for (int j = 0; j < 4; ++j)
        acc[i][j] = __builtin_amdgcn_mfma_f32_16x16x32_f16(av[i], bv[j], acc[i][j], 0, 0, 0);
    __syncthreads();
  }
  const float s1 = scales[e];
  #pragma unroll
  for (int i = 0; i < 4; ++i) {
    #pragma unroll
    for (int r = 0; r < 4; ++r) {
      const int row = m0 + wr + i * 16 + lq * 4 + r;
      const float rs = inv_sx[row] * s1;
      #pragma unroll
      for (int j = 0; j < 4; ++j) {
        const int col = n0 + wc + j * 16 + lm;
        const float h = acc[i][j][r] * rs + b1[e * HID + col];
        const float a = 0.5f * h * (1.0f + erff(h * 0.70710678118654752f));
        outp[(size_t)row * HID + col] = (_Float16)a;
      }
    }
  }
}

// ---------- per-(t,e)-row rmsnorm + act_quant, in place ----------
__global__ __launch_bounds__(256) void rowquant_kernel(
    _Float16* __restrict__ qa, float* __restrict__ inv_sa, int isa_off) {
  __shared__ float buf[4];
  const size_t R = blockIdx.x;
  _Float16* row = qa + R * HID;
  const int tid = threadIdx.x;
  f16x8 v0 = ((const f16x8*)row)[tid * 2];
  f16x8 v1 = ((const f16x8*)row)[tid * 2 + 1];
  float f[16];
  #pragma unroll
  for (int k = 0; k < 8; ++k) { f[k] = (float)v0[k]; f[8 + k] = (float)v1[k]; }
  float ss = 0.0f;
  #pragma unroll
  for (int k = 0; k < 16; ++k) ss += f[k] * f[k];
  ss = block_sum(ss, buf, tid);
  const float rr = 64.0f / fmaxf(sqrtf(ss), 1e-12f); // sqrt(4096)=64
  float am = 0.0f;
  #pragma unroll
  for (int k = 0; k < 16; ++k) am = fmaxf(am, fabsf(f[k] * rr));
  am = block_max(am, buf, tid);
  const float aclip = fmaxf(am, 1e-5f);
  const float qsc = 127.0f / aclip;
  f16x8 o0, o1;
  #pragma unroll
  for (int k = 0; k < 8; ++k) {
    o0[k] = (_Float16)fminf(fmaxf(rintf(f[k] * rr * qsc), -128.0f), 127.0f);
    o1[k] = (_Float16)fminf(fmaxf(rintf(f[8 + k] * rr * qsc), -128.0f), 127.0f);
  }
  ((f16x8*)row)[tid * 2] = o0;
  ((f16x8*)row)[tid * 2 + 1] = o1;
  if (tid == 0) inv_sa[isa_off + (int)R] = aclip / 127.0f;
}

// ---------- GEMM2: out += gate * (qa(int).w2q(tern)*scale + b2) ----------
__global__ __launch_bounds__(256) void gemm2_kernel(
    const _Float16* __restrict__ qa, const _Float16* __restrict__ w2q,
    const float* __restrict__ scales, const float* __restrict__ inv_sa,
    const float* __restrict__ b2, const float* __restrict__ gates,
    float* __restrict__ outp, unsigned long long qa_zstride, int e0) {
  __shared__ __align__(16) _Float16 sA[128 * 32];
  __shared__ __align__(16) _Float16 sB[128 * 32];
  const int e = e0 + blockIdx.z;
  const _Float16* A = qa + (size_t)blockIdx.z * qa_zstride;  // [T][4096]
  const _Float16* Bm = w2q + (size_t)e * DIMS * HID;         // [D][4096]
  const int m0 = blockIdx.x * 128, n0 = blockIdx.y * 128;
  const int tid = threadIdx.x, lane = tid & 63, wv = tid >> 6;
  const int wr = (wv >> 1) * 64, wc = (wv & 1) * 64, lm = lane & 15, lq = lane >> 4;
  f32x4 acc[4][4] = {};
  for (int k0 = 0; k0 < HID; k0 += 32) {
    #pragma unroll
    for (int is = 0; is < 2; ++is) {
      const int c = is * 256 + tid;
      const int row = c >> 2, kc = (c & 3) * 8;
      gl_lds16(A + (size_t)(m0 + row) * HID + k0 + kc, &sA[c * 8]);
      gl_lds16(Bm + (size_t)(n0 + row) * HID + k0 + kc, &sB[c * 8]);
    }
    __syncthreads();
    f16x8 av[4], bv[4];
    #pragma unroll
    for (int i = 0; i < 4; ++i) av[i] = *(const f16x8*)&sA[(wr + i * 16 + lm) * 32 + lq * 8];
    #pragma unroll
    for (int j = 0; j < 4; ++j) bv[j] = *(const f16x8*)&sB[(wc + j * 16 + lm) * 32 + lq * 8];
    #pragma unroll
    for (int i = 0; i < 4; ++i)
      #pragma unroll
      for (int j = 0; j < 4; ++j)
        acc[i][j] = __builtin_amdgcn_mfma_f32_16x16x32_f16(av[i], bv[j], acc[i][j], 0, 0, 0);
    __syncthreads();
  }
  const float s2 = scales[16 + e];
  #pragma unroll
  for (int i = 0; i < 4; ++i) {
    #pragma unroll
    for (int r = 0; r < 4; ++r) {
      const int row = m0 + wr + i * 16 + lq * 4 + r;
      const float rs = inv_sa[e * T_TOK + row] * s2;
      const float g = gates[row * NE + e];
      #pragma unroll
      for (int j = 0; j < 4; ++j) {
        const int col = n0 + wc + j * 16 + lm;
        const float v = acc[i][j][r] * rs + b2[e * DIMS + col];
        atomicAdd(&outp[(size_t)row * DIMS + col], g * v);
      }
    }
  }
}

// ---------- host orchestration ----------
extern "C" void kernel_launch(void* const* d_in, const int* in_sizes, int n_in,
                              void* d_out, int out_size, void* d_ws, size_t ws_size,
                              hipStream_t stream) {
  const float* x  = (const float*)d_in[0];
  const float* gw = (const float*)d_in[1];
  const float* gb = (const float*)d_in[2];
  const float* w1 = (const float*)d_in[3];
  const float* b1 = (const float*)d_in[4];
  const float* w2 = (const float*)d_in[5];
  const float* b2 = (const float*)d_in[6];
  float* outp = (float*)d_out;
  char* ws = (char*)d_ws;

  float* wsum   = (float*)(ws + 0);        // 17 floats (accumulators)
  float* scales = (float*)(ws + 256);      // 34 floats
  float* inv_sx = (float*)(ws + 4096);     // 4096 floats
  float* gates  = (float*)(ws + 20480);    // 32768 floats
  float* inv_sa = (float*)(ws + 151552);   // 32768 floats
  _Float16* qx  = (_Float16*)(ws + 282624);     // 8 MB
  _Float16* w1q = (_Float16*)(ws + 8671232);    // 64 MiB
  _Float16* w2q = (_Float16*)(ws + 75780096);   // 64 MiB
  _Float16* qa  = (_Float16*)(ws + 142888960);  // path A: 256 MiB, path B: 32 MiB

  const bool bigws = ws_size >= 142888960ull + 268435456ull;

  hipMemsetAsync(wsum, 0, 17 * sizeof(float), stream);
  wabs_sum_kernel<<<2048, 256, 0, stream>>>((const float4*)w1, 8388608, 20, wsum + 0);
  wabs_sum_kernel<<<2048, 256, 0, stream>>>((const float4*)w2, 8388608, 20, wsum + 8);
  wabs_sum_kernel<<<1,    256, 0, stream>>>((const float4*)gw, 2048,    30, wsum + 16);
  mkscales_kernel<<<1, 64, 0, stream>>>(wsum, scales);
  wquant_kernel<<<32768, 256, 0, stream>>>((const float4*)w1, w1q, 8388608, 20, scales + 8);
  wquant_kernel<<<32768, 256, 0, stream>>>((const float4*)w2, w2q, 8388608, 20, scales + 24);
  preprocess_kernel<<<4096, 256, 0, stream>>>(x, gw, gb, scales, qx, inv_sx, gates);
  hipMemsetAsync(outp, 0, (size_t)out_size * sizeof(float), stream);

  if (bigws) {
    gemm1_kernel<<<dim3(32, 32, 8), 256, 0, stream>>>(
        qx, w1q, scales, inv_sx, b1, qa, (unsigned long long)T_TOK * HID, 0);
    rowquant_kernel<<<32768, 256, 0, stream>>>(qa, inv_sa, 0);
    gemm2_kernel<<<dim3(32, 8, 8), 256, 0, stream>>>(
        qa, w2q, scales, inv_sa, b2, gates, outp, (unsigned long long)T_TOK * HID, 0);
  } else {
    for (int e = 0; e < NE; ++e) {
      gemm1_kernel<<<dim3(32, 32, 1), 256, 0, stream>>>(
          qx, w1q, scales, inv_sx, b1, qa, 0ull, e);
      rowquant_kernel<<<4096, 256, 0, stream>>>(qa, inv_sa, e * T_TOK);
      gemm2_kernel<<<dim3(32, 8, 1), 256, 0, stream>>>(
          qa, w2q, scales, inv_sa, b2, gates, outp, 0ull, e);
    }
  }
}

// Round 2
// 1018.248 us; speedup vs baseline: 1.3449x; 1.3449x over previous
//
#include <hip/hip_runtime.h>

// BitMoE: dense 8-expert BitNet MoE, T=4096 tokens, D=1024, H=4096.
// Round 2: int8 MFMA path. Quantized activations are exact int8, weights exact
// ternary -> v_mfma_i32_16x16x64_i8 computes the dot products bit-exactly at
// ~2x the f16 MFMA rate with half the staging bytes. Scales fold into fp32
// epilogues. rowquant writes i8 in place into the head of each f16 row.

#define T_TOK 4096
#define DIMS  1024
#define HID   4096
#define NE    8
#define ROWB  8192ull   // byte stride of an a/qa row (4096 f16 = 8192 B; i8 uses first 4096 B)

typedef __attribute__((ext_vector_type(4))) int       i32x4;
typedef __attribute__((ext_vector_type(8))) _Float16  f16x8;
typedef __attribute__((ext_vector_type(4))) _Float16  f16x4;

// ---------- helpers ----------
__device__ __forceinline__ float block_sum(float v, float* buf, int tid) {
  #pragma unroll
  for (int o = 32; o > 0; o >>= 1) v += __shfl_down(v, o, 64);
  __syncthreads();
  if ((tid & 63) == 0) buf[tid >> 6] = v;
  __syncthreads();
  return buf[0] + buf[1] + buf[2] + buf[3];
}
__device__ __forceinline__ float block_max(float v, float* buf, int tid) {
  #pragma unroll
  for (int o = 32; o > 0; o >>= 1) { float t = __shfl_down(v, o, 64); v = fmaxf(v, t); }
  __syncthreads();
  if ((tid & 63) == 0) buf[tid >> 6] = v;
  __syncthreads();
  return fmaxf(fmaxf(buf[0], buf[1]), fmaxf(buf[2], buf[3]));
}

// async global->LDS, 16B per lane; LDS dest = wave-uniform base + lane*16
__device__ __forceinline__ void gl_lds16(const void* g, void* l) {
  __builtin_amdgcn_global_load_lds(
      (const __attribute__((address_space(1))) unsigned int*)g,
      (__attribute__((address_space(3))) unsigned int*)l, 16, 0, 0);
}

__device__ __forceinline__ int q8(float v) {  // round-clip to [-128,127] -> low byte
  return ((int)fminf(fmaxf(rintf(v), -128.0f), 127.0f)) & 0xff;
}

// ---------- weight scale reduction: sum |w| per group ----------
__global__ __launch_bounds__(256) void wabs_sum_kernel(
    const float4* __restrict__ w, int n_f4, int shift, float* __restrict__ sums) {
  __shared__ float buf[4];
  const int tid = threadIdx.x;
  const int base = blockIdx.x * 4096;
  float acc = 0.0f;
  for (int k = 0; k < 16; ++k) {
    int fi = base + k * 256 + tid;
    if (fi < n_f4) {
      float4 v = w[fi];
      acc += fabsf(v.x) + fabsf(v.y) + fabsf(v.z) + fabsf(v.w);
    }
  }
  acc = block_sum(acc, buf, tid);
  if (tid == 0) atomicAdd(&sums[base >> shift], acc);
}

// ---------- scales ----------
__global__ void mkscales_kernel(const float* __restrict__ wsum, float* __restrict__ sc) {
  if (threadIdx.x == 0) {
    #pragma unroll
    for (int e = 0; e < NE; ++e) {
      float m1 = fmaxf(wsum[e] * (1.0f / 4194304.0f), 1e-5f);
      sc[e] = m1; sc[8 + e] = 1.0f / m1;
      float m2 = fmaxf(wsum[8 + e] * (1.0f / 4194304.0f), 1e-5f);
      sc[16 + e] = m2; sc[24 + e] = 1.0f / m2;
    }
    float mg = fmaxf(wsum[16] * (1.0f / 8192.0f), 1e-5f);
    sc[32] = mg; sc[33] = 1.0f / mg;
  }
}

// ---------- ternary weight quant -> i8 {-1,0,1} ----------
__global__ __launch_bounds__(256) void wquant_kernel(
    const float4* __restrict__ w, int* __restrict__ o, int n_f4, int shift,
    const float* __restrict__ qs) {
  int fi = blockIdx.x * 256 + threadIdx.x;
  if (fi >= n_f4) return;
  const float s = qs[fi >> shift];
  float4 v = w[fi];
  int b0 = ((int)fminf(fmaxf(rintf(v.x * s), -1.0f), 1.0f)) & 0xff;
  int b1 = ((int)fminf(fmaxf(rintf(v.y * s), -1.0f), 1.0f)) & 0xff;
  int b2 = ((int)fminf(fmaxf(rintf(v.z * s), -1.0f), 1.0f)) & 0xff;
  int b3 = ((int)fminf(fmaxf(rintf(v.w * s), -1.0f), 1.0f)) & 0xff;
  o[fi] = b0 | (b1 << 8) | (b2 << 16) | (b3 << 24);
}

// ---------- token preprocess: rmsnorm + act_quant(i8) + gate softmax ----------
__global__ __launch_bounds__(256) void preprocess_kernel(
    const float* __restrict__ x, const float* __restrict__ gw,
    const float* __restrict__ gb, const float* __restrict__ scales,
    int* __restrict__ qx, float* __restrict__ inv_sx, float* __restrict__ gates) {
  __shared__ float buf[4];
  const int t = blockIdx.x, tid = threadIdx.x;
  const float4 xv = ((const float4*)(x + (size_t)t * DIMS))[tid];
  float ss = xv.x * xv.x + xv.y * xv.y + xv.z * xv.z + xv.w * xv.w;
  ss = block_sum(ss, buf, tid);
  const float rr = 32.0f / fmaxf(sqrtf(ss), 1e-12f); // sqrt(1024)=32
  const float y0 = xv.x * rr, y1 = xv.y * rr, y2 = xv.z * rr, y3 = xv.w * rr;
  float am = fmaxf(fmaxf(fabsf(y0), fabsf(y1)), fmaxf(fabsf(y2), fabsf(y3)));
  am = block_max(am, buf, tid);
  const float aclip = fmaxf(am, 1e-5f);
  const float qsc = 127.0f / aclip;
  const float q0 = fminf(fmaxf(rintf(y0 * qsc), -128.0f), 127.0f);
  const float q1 = fminf(fmaxf(rintf(y1 * qsc), -128.0f), 127.0f);
  const float q2 = fminf(fmaxf(rintf(y2 * qsc), -128.0f), 127.0f);
  const float q3 = fminf(fmaxf(rintf(y3 * qsc), -128.0f), 127.0f);
  qx[t * 256 + tid] = (((int)q0) & 0xff) | ((((int)q1) & 0xff) << 8) |
                      ((((int)q2) & 0xff) << 16) | ((((int)q3) & 0xff) << 24);

  // gate logits: exact integer dots with on-the-fly ternary gw
  const float gsabs = scales[32], gqs = scales[33];
  float lg[NE];
  #pragma unroll
  for (int e = 0; e < NE; ++e) {
    const float4 gv = ((const float4*)(gw + e * DIMS))[tid];
    float t0 = fminf(fmaxf(rintf(gv.x * gqs), -1.0f), 1.0f);
    float t1 = fminf(fmaxf(rintf(gv.y * gqs), -1.0f), 1.0f);
    float t2 = fminf(fmaxf(rintf(gv.z * gqs), -1.0f), 1.0f);
    float t3 = fminf(fmaxf(rintf(gv.w * gqs), -1.0f), 1.0f);
    lg[e] = q0 * t0 + q1 * t1 + q2 * t2 + q3 * t3;
  }
  #pragma unroll
  for (int e = 0; e < NE; ++e) lg[e] = block_sum(lg[e], buf, tid);
  if (tid == 0) {
    const float isx = aclip / 127.0f;
    inv_sx[t] = isx;
    float l[NE], mx = -1e30f;
    #pragma unroll
    for (int e = 0; e < NE; ++e) { l[e] = lg[e] * (isx * gsabs) + gb[e]; mx = fmaxf(mx, l[e]); }
    float s = 0.0f;
    #pragma unroll
    for (int e = 0; e < NE; ++e) { l[e] = expf(l[e] - mx); s += l[e]; }
    const float inv = 1.0f / s;
    #pragma unroll
    for (int e = 0; e < NE; ++e) gates[t * NE + e] = l[e] * inv;
  }
}

// ---------- GEMM1 (i8): h = qx . w1q, epilogue scale+bias+GELU -> f16 row ----------
__global__ __launch_bounds__(256) void gemm1_kernel(
    const char* __restrict__ qx, const char* __restrict__ w1q,
    const float* __restrict__ scales, const float* __restrict__ inv_sx,
    const float* __restrict__ b1, char* __restrict__ aqa) {
  __shared__ __align__(16) char sA[128 * 64];
  __shared__ __align__(16) char sB[128 * 64];
  const int e = blockIdx.z;
  const char* A = qx;                                   // [T][1024] i8
  const char* Bm = w1q + (size_t)e * HID * DIMS;        // [H][1024] i8
  char* obase = aqa + (size_t)e * T_TOK * ROWB;         // [T] rows of 8192 B (f16)
  const int m0 = blockIdx.x * 128, n0 = blockIdx.y * 128;
  const int tid = threadIdx.x, lane = tid & 63, wv = tid >> 6;
  const int wr = (wv >> 1) * 64, wc = (wv & 1) * 64, lm = lane & 15, lq = lane >> 4;
  i32x4 acc[4][4] = {};
  for (int k0 = 0; k0 < DIMS; k0 += 64) {
    #pragma unroll
    for (int is = 0; is < 2; ++is) {
      const int c = is * 256 + tid;
      const int row = c >> 2, kc = (c & 3) * 16;
      gl_lds16(A + (size_t)(m0 + row) * DIMS + k0 + kc, &sA[c * 16]);
      gl_lds16(Bm + (size_t)(n0 + row) * DIMS + k0 + kc, &sB[c * 16]);
    }
    __syncthreads();
    i32x4 av[4], bv[4];
    #pragma unroll
    for (int i = 0; i < 4; ++i) av[i] = *(const i32x4*)&sA[(wr + i * 16 + lm) * 64 + lq * 16];
    #pragma unroll
    for (int j = 0; j < 4; ++j) bv[j] = *(const i32x4*)&sB[(wc + j * 16 + lm) * 64 + lq * 16];
    #pragma unroll
    for (int i = 0; i < 4; ++i)
      #pragma unroll
      for (int j = 0; j < 4; ++j)
        acc[i][j] = __builtin_amdgcn_mfma_i32_16x16x64_i8(av[i], bv[j], acc[i][j], 0, 0, 0);
    __syncthreads();
  }
  const float s1 = scales[e];
  #pragma unroll
  for (int i = 0; i < 4; ++i) {
    #pragma unroll
    for (int r = 0; r < 4; ++r) {
      const int row = m0 + wr + i * 16 + lq * 4 + r;
      const float rs = inv_sx[row] * s1;
      _Float16* orow = (_Float16*)(obase + (size_t)row * ROWB);
      #pragma unroll
      for (int j = 0; j < 4; ++j) {
        const int col = n0 + wc + j * 16 + lm;
        const float h = (float)acc[i][j][r] * rs + b1[e * HID + col];
        const float a = 0.5f * h * (1.0f + erff(h * 0.70710678118654752f));
        orow[col] = (_Float16)a;
      }
    }
  }
}

// ---------- per-row rmsnorm + act_quant: f16 row -> i8 in place ----------
__global__ __launch_bounds__(256) void rowquant_kernel(
    char* __restrict__ aqa, float* __restrict__ inv_sa) {
  __shared__ float buf[4];
  const size_t R = blockIdx.x;
  char* rowb = aqa + R * ROWB;
  const int tid = threadIdx.x;
  f16x8 v0 = ((const f16x8*)rowb)[tid * 2];
  f16x8 v1 = ((const f16x8*)rowb)[tid * 2 + 1];
  float f[16];
  #pragma unroll
  for (int k = 0; k < 8; ++k) { f[k] = (float)v0[k]; f[8 + k] = (float)v1[k]; }
  float ss = 0.0f;
  #pragma unroll
  for (int k = 0; k < 16; ++k) ss += f[k] * f[k];
  ss = block_sum(ss, buf, tid);           // barrier: all reads complete before any write below
  const float rr = 64.0f / fmaxf(sqrtf(ss), 1e-12f); // sqrt(4096)=64
  float am = 0.0f;
  #pragma unroll
  for (int k = 0; k < 16; ++k) am = fmaxf(am, fabsf(f[k] * rr));
  am = block_max(am, buf, tid);
  const float aclip = fmaxf(am, 1e-5f);
  const float qsc = rr * 127.0f / aclip;
  int4 o;
  o.x = q8(f[0] * qsc) | (q8(f[1] * qsc) << 8) | (q8(f[2] * qsc) << 16) | (q8(f[3] * qsc) << 24);
  o.y = q8(f[4] * qsc) | (q8(f[5] * qsc) << 8) | (q8(f[6] * qsc) << 16) | (q8(f[7] * qsc) << 24);
  o.z = q8(f[8] * qsc) | (q8(f[9] * qsc) << 8) | (q8(f[10] * qsc) << 16) | (q8(f[11] * qsc) << 24);
  o.w = q8(f[12] * qsc) | (q8(f[13] * qsc) << 8) | (q8(f[14] * qsc) << 16) | (q8(f[15] * qsc) << 24);
  ((int4*)rowb)[tid] = o;
  if (tid == 0) inv_sa[R] = aclip / 127.0f;
}

// ---------- GEMM2 (i8): per-expert out tile -> f32 scratch (or atomicAdd) ----------
__global__ __launch_bounds__(256) void gemm2_kernel(
    const char* __restrict__ aqa, const char* __restrict__ w2q,
    const float* __restrict__ scales, const float* __restrict__ inv_sa,
    const float* __restrict__ b2, const float* __restrict__ gates,
    float* __restrict__ dst, int use_atomic) {
  __shared__ __align__(16) char sA[128 * 64];
  __shared__ __align__(16) char sB[128 * 64];
  const int e = blockIdx.z;
  const char* A = aqa + (size_t)e * T_TOK * ROWB;        // [T] rows, i8 in first 4096 B
  const char* Bm = w2q + (size_t)e * DIMS * HID;         // [D][4096] i8
  const int n0 = blockIdx.x * 128, m0 = blockIdx.y * 128; // x=n so 8 consecutive blocks share A tile
  const int tid = threadIdx.x, lane = tid & 63, wv = tid >> 6;
  const int wr = (wv >> 1) * 64, wc = (wv & 1) * 64, lm = lane & 15, lq = lane >> 4;
  i32x4 acc[4][4] = {};
  for (int k0 = 0; k0 < HID; k0 += 64) {
    #pragma unroll
    for (int is = 0; is < 2; ++is) {
      const int c = is * 256 + tid;
      const int row = c >> 2, kc = (c & 3) * 16;
      gl_lds16(A + (size_t)(m0 + row) * ROWB + k0 + kc, &sA[c * 16]);
      gl_lds16(Bm + (size_t)(n0 + row) * HID + k0 + kc, &sB[c * 16]);
    }
    __syncthreads();
    i32x4 av[4], bv[4];
    #pragma unroll
    for (int i = 0; i < 4; ++i) av[i] = *(const i32x4*)&sA[(wr + i * 16 + lm) * 64 + lq * 16];
    #pragma unroll
    for (int j = 0; j < 4; ++j) bv[j] = *(const i32x4*)&sB[(wc + j * 16 + lm) * 64 + lq * 16];
    #pragma unroll
    for (int i = 0; i < 4; ++i)
      #pragma unroll
      for (int j = 0; j < 4; ++j)
        acc[i][j] = __builtin_amdgcn_mfma_i32_16x16x64_i8(av[i], bv[j], acc[i][j], 0, 0, 0);
    __syncthreads();
  }
  const float s2 = scales[16 + e];
  #pragma unroll
  for (int i = 0; i < 4; ++i) {
    #pragma unroll
    for (int r = 0; r < 4; ++r) {
      const int row = m0 + wr + i * 16 + lq * 4 + r;
      const float rs = inv_sa[(size_t)e * T_TOK + row] * s2;
      const float g = gates[row * NE + e];
      #pragma unroll
      for (int j = 0; j < 4; ++j) {
        const int col = n0 + wc + j * 16 + lm;
        const float v = g * ((float)acc[i][j][r] * rs + b2[e * DIMS + col]);
        if (use_atomic) atomicAdd(&dst[(size_t)row * DIMS + col], v);
        else dst[((size_t)e * T_TOK + row) * DIMS + col] = v;
      }
    }
  }
}

// ---------- expert-sum reduce ----------
__global__ __launch_bounds__(256) void reduce_kernel(
    const float4* __restrict__ eout, float4* __restrict__ out) {
  const int i = blockIdx.x * 256 + threadIdx.x;  // over T*D/4 = 1048576
  float4 s = eout[i];
  #pragma unroll
  for (int e = 1; e < NE; ++e) {
    float4 v = eout[(size_t)e * (T_TOK * DIMS / 4) + i];
    s.x += v.x; s.y += v.y; s.z += v.z; s.w += v.w;
  }
  out[i] = s;
}

// ---------- host orchestration ----------
extern "C" void kernel_launch(void* const* d_in, const int* in_sizes, int n_in,
                              void* d_out, int out_size, void* d_ws, size_t ws_size,
                              hipStream_t stream) {
  const float* x  = (const float*)d_in[0];
  const float* gw = (const float*)d_in[1];
  const float* gb = (const float*)d_in[2];
  const float* w1 = (const float*)d_in[3];
  const float* b1 = (const float*)d_in[4];
  const float* w2 = (const float*)d_in[5];
  const float* b2 = (const float*)d_in[6];
  float* outp = (float*)d_out;
  char* ws = (char*)d_ws;

  float* wsum   = (float*)(ws + 0);        // 17 floats
  float* scales = (float*)(ws + 256);      // 34 floats
  float* inv_sx = (float*)(ws + 4096);     // 4096 floats
  float* gates  = (float*)(ws + 20480);    // 32768 floats
  float* inv_sa = (float*)(ws + 151552);   // 32768 floats
  char*  qx     = ws + 282624;             // 4 MiB i8 [T][1024]
  char*  w1q    = ws + 4476928;            // 32 MiB i8
  char*  w2q    = ws + 38031360;           // 32 MiB i8
  char*  aqa    = ws + 71585792;           // 256 MiB: [E*T] rows of 8192 B
  float* eout   = (float*)(ws + 340021248);// 128 MiB f32 [E][T][D] (optional)

  const bool has_eout = ws_size >= 474238976ull;

  hipMemsetAsync(wsum, 0, 17 * sizeof(float), stream);
  wabs_sum_kernel<<<2048, 256, 0, stream>>>((const float4*)w1, 8388608, 20, wsum + 0);
  wabs_sum_kernel<<<2048, 256, 0, stream>>>((const float4*)w2, 8388608, 20, wsum + 8);
  wabs_sum_kernel<<<1,    256, 0, stream>>>((const float4*)gw, 2048,    30, wsum + 16);
  mkscales_kernel<<<1, 64, 0, stream>>>(wsum, scales);
  wquant_kernel<<<32768, 256, 0, stream>>>((const float4*)w1, (int*)w1q, 8388608, 20, scales + 8);
  wquant_kernel<<<32768, 256, 0, stream>>>((const float4*)w2, (int*)w2q, 8388608, 20, scales + 24);
  preprocess_kernel<<<4096, 256, 0, stream>>>(x, gw, gb, scales, (int*)qx, inv_sx, gates);

  gemm1_kernel<<<dim3(32, 32, 8), 256, 0, stream>>>(qx, w1q, scales, inv_sx, b1, aqa);
  rowquant_kernel<<<32768, 256, 0, stream>>>(aqa, inv_sa);

  if (has_eout) {
    gemm2_kernel<<<dim3(8, 32, 8), 256, 0, stream>>>(
        aqa, w2q, scales, inv_sa, b2, gates, eout, 0);
    reduce_kernel<<<4096, 256, 0, stream>>>((const float4*)eout, (float4*)outp);
  } else {
    hipMemsetAsync(outp, 0, (size_t)out_size * sizeof(float), stream);
    gemm2_kernel<<<dim3(8, 32, 8), 256, 0, stream>>>(
        aqa, w2q, scales, inv_sa, b2, gates, outp, 1);
  }
}

// Round 3
// 939.494 us; speedup vs baseline: 1.4577x; 1.0838x over previous
//
#include <hip/hip_runtime.h>

// BitMoE: dense 8-expert BitNet MoE, T=4096 tokens, D=1024, H=4096.
// Round 3: i8 MFMA GEMMs restructured to 256x128 tiles, BK=128, XOR-swizzled
// LDS (conflict-free ds_read_b128), 64 MFMA per wave per barrier. Integer math
// is bit-exact; scales fold into fp32 epilogues.

#define T_TOK 4096
#define DIMS  1024
#define HID   4096
#define NE    8
#define ROWB  8192ull   // byte stride of an a/qa row (4096 f16; i8 uses first 4096 B)

typedef __attribute__((ext_vector_type(4))) int       i32x4;
typedef __attribute__((ext_vector_type(8))) _Float16  f16x8;

// ---------- helpers ----------
__device__ __forceinline__ float block_sum(float v, float* buf, int tid) {
  #pragma unroll
  for (int o = 32; o > 0; o >>= 1) v += __shfl_down(v, o, 64);
  __syncthreads();
  if ((tid & 63) == 0) buf[tid >> 6] = v;
  __syncthreads();
  return buf[0] + buf[1] + buf[2] + buf[3];
}
__device__ __forceinline__ float block_max(float v, float* buf, int tid) {
  #pragma unroll
  for (int o = 32; o > 0; o >>= 1) { float t = __shfl_down(v, o, 64); v = fmaxf(v, t); }
  __syncthreads();
  if ((tid & 63) == 0) buf[tid >> 6] = v;
  __syncthreads();
  return fmaxf(fmaxf(buf[0], buf[1]), fmaxf(buf[2], buf[3]));
}

// async global->LDS, 16B per lane; LDS dest = wave-uniform base + lane*16
__device__ __forceinline__ void gl_lds16(const void* g, void* l) {
  __builtin_amdgcn_global_load_lds(
      (const __attribute__((address_space(1))) unsigned int*)g,
      (__attribute__((address_space(3))) unsigned int*)l, 16, 0, 0);
}

__device__ __forceinline__ int q8(float v) {
  return ((int)fminf(fmaxf(rintf(v), -128.0f), 127.0f)) & 0xff;
}

// swizzled fragment address: row stride 128 B, chunk' = chunk ^ (row&7)
__device__ __forceinline__ const i32x4* frag(const char* s, int row, int ckW) {
  return (const i32x4*)&s[row * 128 + ((ckW ^ (row & 7)) << 4)];
}

// ---------- weight scale reduction: sum |w| per group ----------
__global__ __launch_bounds__(256) void wabs_sum_kernel(
    const float4* __restrict__ w, int n_f4, int shift, float* __restrict__ sums) {
  __shared__ float buf[4];
  const int tid = threadIdx.x;
  const int base = blockIdx.x * 4096;
  float acc = 0.0f;
  for (int k = 0; k < 16; ++k) {
    int fi = base + k * 256 + tid;
    if (fi < n_f4) {
      float4 v = w[fi];
      acc += fabsf(v.x) + fabsf(v.y) + fabsf(v.z) + fabsf(v.w);
    }
  }
  acc = block_sum(acc, buf, tid);
  if (tid == 0) atomicAdd(&sums[base >> shift], acc);
}

// ---------- scales ----------
__global__ void mkscales_kernel(const float* __restrict__ wsum, float* __restrict__ sc) {
  if (threadIdx.x == 0) {
    #pragma unroll
    for (int e = 0; e < NE; ++e) {
      float m1 = fmaxf(wsum[e] * (1.0f / 4194304.0f), 1e-5f);
      sc[e] = m1; sc[8 + e] = 1.0f / m1;
      float m2 = fmaxf(wsum[8 + e] * (1.0f / 4194304.0f), 1e-5f);
      sc[16 + e] = m2; sc[24 + e] = 1.0f / m2;
    }
    float mg = fmaxf(wsum[16] * (1.0f / 8192.0f), 1e-5f);
    sc[32] = mg; sc[33] = 1.0f / mg;
  }
}

// ---------- ternary weight quant -> i8 {-1,0,1} ----------
__global__ __launch_bounds__(256) void wquant_kernel(
    const float4* __restrict__ w, int* __restrict__ o, int n_f4, int shift,
    const float* __restrict__ qs) {
  int fi = blockIdx.x * 256 + threadIdx.x;
  if (fi >= n_f4) return;
  const float s = qs[fi >> shift];
  float4 v = w[fi];
  int b0 = ((int)fminf(fmaxf(rintf(v.x * s), -1.0f), 1.0f)) & 0xff;
  int b1 = ((int)fminf(fmaxf(rintf(v.y * s), -1.0f), 1.0f)) & 0xff;
  int b2 = ((int)fminf(fmaxf(rintf(v.z * s), -1.0f), 1.0f)) & 0xff;
  int b3 = ((int)fminf(fmaxf(rintf(v.w * s), -1.0f), 1.0f)) & 0xff;
  o[fi] = b0 | (b1 << 8) | (b2 << 16) | (b3 << 24);
}

// ---------- token preprocess: rmsnorm + act_quant(i8) + gate softmax ----------
__global__ __launch_bounds__(256) void preprocess_kernel(
    const float* __restrict__ x, const float* __restrict__ gw,
    const float* __restrict__ gb, const float* __restrict__ scales,
    int* __restrict__ qx, float* __restrict__ inv_sx, float* __restrict__ gates) {
  __shared__ float buf[4];
  const int t = blockIdx.x, tid = threadIdx.x;
  const float4 xv = ((const float4*)(x + (size_t)t * DIMS))[tid];
  float ss = xv.x * xv.x + xv.y * xv.y + xv.z * xv.z + xv.w * xv.w;
  ss = block_sum(ss, buf, tid);
  const float rr = 32.0f / fmaxf(sqrtf(ss), 1e-12f); // sqrt(1024)=32
  const float y0 = xv.x * rr, y1 = xv.y * rr, y2 = xv.z * rr, y3 = xv.w * rr;
  float am = fmaxf(fmaxf(fabsf(y0), fabsf(y1)), fmaxf(fabsf(y2), fabsf(y3)));
  am = block_max(am, buf, tid);
  const float aclip = fmaxf(am, 1e-5f);
  const float qsc = 127.0f / aclip;
  const float q0 = fminf(fmaxf(rintf(y0 * qsc), -128.0f), 127.0f);
  const float q1 = fminf(fmaxf(rintf(y1 * qsc), -128.0f), 127.0f);
  const float q2 = fminf(fmaxf(rintf(y2 * qsc), -128.0f), 127.0f);
  const float q3 = fminf(fmaxf(rintf(y3 * qsc), -128.0f), 127.0f);
  qx[t * 256 + tid] = (((int)q0) & 0xff) | ((((int)q1) & 0xff) << 8) |
                      ((((int)q2) & 0xff) << 16) | ((((int)q3) & 0xff) << 24);

  const float gsabs = scales[32], gqs = scales[33];
  float lg[NE];
  #pragma unroll
  for (int e = 0; e < NE; ++e) {
    const float4 gv = ((const float4*)(gw + e * DIMS))[tid];
    float t0 = fminf(fmaxf(rintf(gv.x * gqs), -1.0f), 1.0f);
    float t1 = fminf(fmaxf(rintf(gv.y * gqs), -1.0f), 1.0f);
    float t2 = fminf(fmaxf(rintf(gv.z * gqs), -1.0f), 1.0f);
    float t3 = fminf(fmaxf(rintf(gv.w * gqs), -1.0f), 1.0f);
    lg[e] = q0 * t0 + q1 * t1 + q2 * t2 + q3 * t3;
  }
  #pragma unroll
  for (int e = 0; e < NE; ++e) lg[e] = block_sum(lg[e], buf, tid);
  if (tid == 0) {
    const float isx = aclip / 127.0f;
    inv_sx[t] = isx;
    float l[NE], mx = -1e30f;
    #pragma unroll
    for (int e = 0; e < NE; ++e) { l[e] = lg[e] * (isx * gsabs) + gb[e]; mx = fmaxf(mx, l[e]); }
    float s = 0.0f;
    #pragma unroll
    for (int e = 0; e < NE; ++e) { l[e] = expf(l[e] - mx); s += l[e]; }
    const float inv = 1.0f / s;
    #pragma unroll
    for (int e = 0; e < NE; ++e) gates[t * NE + e] = l[e] * inv;
  }
}

// ---------- GEMM1 (i8, 256x128, BK=128): h = qx . w1q, +bias +GELU -> f16 ----------
__global__ __launch_bounds__(256, 2) void gemm1_kernel(
    const char* __restrict__ qx, const char* __restrict__ w1q,
    const float* __restrict__ scales, const float* __restrict__ inv_sx,
    const float* __restrict__ b1, char* __restrict__ aqa) {
  __shared__ __align__(16) char sA[256 * 128];
  __shared__ __align__(16) char sB[128 * 128];
  const int e = blockIdx.z;
  const char* A = qx;                                   // [T][1024] i8
  const char* Bm = w1q + (size_t)e * HID * DIMS;        // [H][1024] i8
  char* obase = aqa + (size_t)e * T_TOK * ROWB;
  const int n0 = blockIdx.x * 128, m0 = blockIdx.y * 256;
  const int tid = threadIdx.x, lane = tid & 63, wv = tid >> 6;
  const int wr = (wv >> 1) * 128, wc = (wv & 1) * 64, lm = lane & 15, lq = lane >> 4;
  i32x4 acc[8][4] = {};
  for (int k0 = 0; k0 < DIMS; k0 += 128) {
    #pragma unroll
    for (int it = 0; it < 8; ++it) {   // sA: 256 rows x 128 B
      const int c = it * 256 + tid;
      const int row = c >> 3, ckG = (c & 7) ^ (row & 7);
      gl_lds16(A + (size_t)(m0 + row) * DIMS + k0 + ckG * 16, &sA[c * 16]);
    }
    #pragma unroll
    for (int it = 0; it < 4; ++it) {   // sB: 128 rows x 128 B
      const int c = it * 256 + tid;
      const int row = c >> 3, ckG = (c & 7) ^ (row & 7);
      gl_lds16(Bm + (size_t)(n0 + row) * DIMS + k0 + ckG * 16, &sB[c * 16]);
    }
    __syncthreads();
    #pragma unroll
    for (int kk = 0; kk < 2; ++kk) {
      i32x4 av[8], bv[4];
      const int ckW = kk * 4 + lq;
      #pragma unroll
      for (int i = 0; i < 8; ++i) av[i] = *frag(sA, wr + i * 16 + lm, ckW);
      #pragma unroll
      for (int j = 0; j < 4; ++j) bv[j] = *frag(sB, wc + j * 16 + lm, ckW);
      #pragma unroll
      for (int i = 0; i < 8; ++i)
        #pragma unroll
        for (int j = 0; j < 4; ++j)
          acc[i][j] = __builtin_amdgcn_mfma_i32_16x16x64_i8(av[i], bv[j], acc[i][j], 0, 0, 0);
    }
    __syncthreads();
  }
  const float s1 = scales[e];
  #pragma unroll
  for (int i = 0; i < 8; ++i) {
    #pragma unroll
    for (int r = 0; r < 4; ++r) {
      const int row = m0 + wr + i * 16 + lq * 4 + r;
      const float rs = inv_sx[row] * s1;
      _Float16* orow = (_Float16*)(obase + (size_t)row * ROWB);
      #pragma unroll
      for (int j = 0; j < 4; ++j) {
        const int col = n0 + wc + j * 16 + lm;
        const float h = (float)acc[i][j][r] * rs + b1[e * HID + col];
        const float a = 0.5f * h * (1.0f + erff(h * 0.70710678118654752f));
        orow[col] = (_Float16)a;
      }
    }
  }
}

// ---------- per-row rmsnorm + act_quant: f16 row -> i8 in place ----------
__global__ __launch_bounds__(256) void rowquant_kernel(
    char* __restrict__ aqa, float* __restrict__ inv_sa) {
  __shared__ float buf[4];
  const size_t R = blockIdx.x;
  char* rowb = aqa + R * ROWB;
  const int tid = threadIdx.x;
  f16x8 v0 = ((const f16x8*)rowb)[tid * 2];
  f16x8 v1 = ((const f16x8*)rowb)[tid * 2 + 1];
  float f[16];
  #pragma unroll
  for (int k = 0; k < 8; ++k) { f[k] = (float)v0[k]; f[8 + k] = (float)v1[k]; }
  float ss = 0.0f;
  #pragma unroll
  for (int k = 0; k < 16; ++k) ss += f[k] * f[k];
  ss = block_sum(ss, buf, tid);           // barrier: reads complete before writes below
  const float rr = 64.0f / fmaxf(sqrtf(ss), 1e-12f); // sqrt(4096)=64
  float am = 0.0f;
  #pragma unroll
  for (int k = 0; k < 16; ++k) am = fmaxf(am, fabsf(f[k] * rr));
  am = block_max(am, buf, tid);
  const float aclip = fmaxf(am, 1e-5f);
  const float qsc = rr * 127.0f / aclip;
  int4 o;
  o.x = q8(f[0] * qsc) | (q8(f[1] * qsc) << 8) | (q8(f[2] * qsc) << 16) | (q8(f[3] * qsc) << 24);
  o.y = q8(f[4] * qsc) | (q8(f[5] * qsc) << 8) | (q8(f[6] * qsc) << 16) | (q8(f[7] * qsc) << 24);
  o.z = q8(f[8] * qsc) | (q8(f[9] * qsc) << 8) | (q8(f[10] * qsc) << 16) | (q8(f[11] * qsc) << 24);
  o.w = q8(f[12] * qsc) | (q8(f[13] * qsc) << 8) | (q8(f[14] * qsc) << 16) | (q8(f[15] * qsc) << 24);
  ((int4*)rowb)[tid] = o;
  if (tid == 0) inv_sa[R] = aclip / 127.0f;
}

// ---------- GEMM2 (i8, 256x128, BK=128): eout = gate*(qa.w2q*scale + b2) ----------
__global__ __launch_bounds__(256, 2) void gemm2_kernel(
    const char* __restrict__ aqa, const char* __restrict__ w2q,
    const float* __restrict__ scales, const float* __restrict__ inv_sa,
    const float* __restrict__ b2, const float* __restrict__ gates,
    float* __restrict__ dst, int use_atomic) {
  __shared__ __align__(16) char sA[256 * 128];
  __shared__ __align__(16) char sB[128 * 128];
  const int e = blockIdx.z;
  const char* A = aqa + (size_t)e * T_TOK * ROWB;        // [T] rows, i8 in first 4096 B
  const char* Bm = w2q + (size_t)e * DIMS * HID;         // [D][4096] i8
  const int n0 = blockIdx.x * 128, m0 = blockIdx.y * 256;
  const int tid = threadIdx.x, lane = tid & 63, wv = tid >> 6;
  const int wr = (wv >> 1) * 128, wc = (wv & 1) * 64, lm = lane & 15, lq = lane >> 4;
  i32x4 acc[8][4] = {};
  for (int k0 = 0; k0 < HID; k0 += 128) {
    #pragma unroll
    for (int it = 0; it < 8; ++it) {
      const int c = it * 256 + tid;
      const int row = c >> 3, ckG = (c & 7) ^ (row & 7);
      gl_lds16(A + (size_t)(m0 + row) * ROWB + k0 + ckG * 16, &sA[c * 16]);
    }
    #pragma unroll
    for (int it = 0; it < 4; ++it) {
      const int c = it * 256 + tid;
      const int row = c >> 3, ckG = (c & 7) ^ (row & 7);
      gl_lds16(Bm + (size_t)(n0 + row) * HID + k0 + ckG * 16, &sB[c * 16]);
    }
    __syncthreads();
    #pragma unroll
    for (int kk = 0; kk < 2; ++kk) {
      i32x4 av[8], bv[4];
      const int ckW = kk * 4 + lq;
      #pragma unroll
      for (int i = 0; i < 8; ++i) av[i] = *frag(sA, wr + i * 16 + lm, ckW);
      #pragma unroll
      for (int j = 0; j < 4; ++j) bv[j] = *frag(sB, wc + j * 16 + lm, ckW);
      #pragma unroll
      for (int i = 0; i < 8; ++i)
        #pragma unroll
        for (int j = 0; j < 4; ++j)
          acc[i][j] = __builtin_amdgcn_mfma_i32_16x16x64_i8(av[i], bv[j], acc[i][j], 0, 0, 0);
    }
    __syncthreads();
  }
  const float s2 = scales[16 + e];
  #pragma unroll
  for (int i = 0; i < 8; ++i) {
    #pragma unroll
    for (int r = 0; r < 4; ++r) {
      const int row = m0 + wr + i * 16 + lq * 4 + r;
      const float rs = inv_sa[(size_t)e * T_TOK + row] * s2;
      const float g = gates[row * NE + e];
      #pragma unroll
      for (int j = 0; j < 4; ++j) {
        const int col = n0 + wc + j * 16 + lm;
        const float v = g * ((float)acc[i][j][r] * rs + b2[e * DIMS + col]);
        if (use_atomic) atomicAdd(&dst[(size_t)row * DIMS + col], v);
        else dst[((size_t)e * T_TOK + row) * DIMS + col] = v;
      }
    }
  }
}

// ---------- expert-sum reduce ----------
__global__ __launch_bounds__(256) void reduce_kernel(
    const float4* __restrict__ eout, float4* __restrict__ out) {
  const int i = blockIdx.x * 256 + threadIdx.x;  // over T*D/4 = 1048576
  float4 s = eout[i];
  #pragma unroll
  for (int e = 1; e < NE; ++e) {
    float4 v = eout[(size_t)e * (T_TOK * DIMS / 4) + i];
    s.x += v.x; s.y += v.y; s.z += v.z; s.w += v.w;
  }
  out[i] = s;
}

// ---------- host orchestration ----------
extern "C" void kernel_launch(void* const* d_in, const int* in_sizes, int n_in,
                              void* d_out, int out_size, void* d_ws, size_t ws_size,
                              hipStream_t stream) {
  const float* x  = (const float*)d_in[0];
  const float* gw = (const float*)d_in[1];
  const float* gb = (const float*)d_in[2];
  const float* w1 = (const float*)d_in[3];
  const float* b1 = (const float*)d_in[4];
  const float* w2 = (const float*)d_in[5];
  const float* b2 = (const float*)d_in[6];
  float* outp = (float*)d_out;
  char* ws = (char*)d_ws;

  float* wsum   = (float*)(ws + 0);        // 17 floats
  float* scales = (float*)(ws + 256);      // 34 floats
  float* inv_sx = (float*)(ws + 4096);     // 4096 floats
  float* gates  = (float*)(ws + 20480);    // 32768 floats
  float* inv_sa = (float*)(ws + 151552);   // 32768 floats
  char*  qx     = ws + 282624;             // 4 MiB i8 [T][1024]
  char*  w1q    = ws + 4476928;            // 32 MiB i8
  char*  w2q    = ws + 38031360;           // 32 MiB i8
  char*  aqa    = ws + 71585792;           // 256 MiB: [E*T] rows of 8192 B
  float* eout   = (float*)(ws + 340021248);// 128 MiB f32 [E][T][D] (optional)

  const bool has_eout = ws_size >= 474238976ull;

  hipMemsetAsync(wsum, 0, 17 * sizeof(float), stream);
  wabs_sum_kernel<<<2048, 256, 0, stream>>>((const float4*)w1, 8388608, 20, wsum + 0);
  wabs_sum_kernel<<<2048, 256, 0, stream>>>((const float4*)w2, 8388608, 20, wsum + 8);
  wabs_sum_kernel<<<1,    256, 0, stream>>>((const float4*)gw, 2048,    30, wsum + 16);
  mkscales_kernel<<<1, 64, 0, stream>>>(wsum, scales);
  wquant_kernel<<<32768, 256, 0, stream>>>((const float4*)w1, (int*)w1q, 8388608, 20, scales + 8);
  wquant_kernel<<<32768, 256, 0, stream>>>((const float4*)w2, (int*)w2q, 8388608, 20, scales + 24);
  preprocess_kernel<<<4096, 256, 0, stream>>>(x, gw, gb, scales, (int*)qx, inv_sx, gates);

  gemm1_kernel<<<dim3(32, 16, 8), 256, 0, stream>>>(qx, w1q, scales, inv_sx, b1, aqa);
  rowquant_kernel<<<32768, 256, 0, stream>>>(aqa, inv_sa);

  if (has_eout) {
    gemm2_kernel<<<dim3(8, 16, 8), 256, 0, stream>>>(
        aqa, w2q, scales, inv_sa, b2, gates, eout, 0);
    reduce_kernel<<<4096, 256, 0, stream>>>((const float4*)eout, (float4*)outp);
  } else {
    hipMemsetAsync(outp, 0, (size_t)out_size * sizeof(float), stream);
    gemm2_kernel<<<dim3(8, 16, 8), 256, 0, stream>>>(
        aqa, w2q, scales, inv_sa, b2, gates, outp, 1);
  }
}

// Round 4
// 891.944 us; speedup vs baseline: 1.5354x; 1.0533x over previous
//
#include <hip/hip_runtime.h>

// BitMoE: dense 8-expert BitNet MoE, T=4096 tokens, D=1024, H=4096.
// Round 4: GELU moved out of gemm1 (compute-bound) into rowquant (memory-bound,
// idle VALU) using a branch-free erf approximation; eout scratch f32 -> f16.
// i8 MFMA GEMMs: 256x128 tiles, BK=128, XOR-swizzled LDS (0 bank conflicts).

#define T_TOK 4096
#define DIMS  1024
#define HID   4096
#define NE    8
#define ROWB  8192ull   // byte stride of an h/qa row (4096 f16; i8 uses first 4096 B)

typedef __attribute__((ext_vector_type(4))) int       i32x4;
typedef __attribute__((ext_vector_type(8))) _Float16  f16x8;

// ---------- helpers ----------
__device__ __forceinline__ float block_sum(float v, float* buf, int tid) {
  #pragma unroll
  for (int o = 32; o > 0; o >>= 1) v += __shfl_down(v, o, 64);
  __syncthreads();
  if ((tid & 63) == 0) buf[tid >> 6] = v;
  __syncthreads();
  return buf[0] + buf[1] + buf[2] + buf[3];
}
__device__ __forceinline__ float block_max(float v, float* buf, int tid) {
  #pragma unroll
  for (int o = 32; o > 0; o >>= 1) { float t = __shfl_down(v, o, 64); v = fmaxf(v, t); }
  __syncthreads();
  if ((tid & 63) == 0) buf[tid >> 6] = v;
  __syncthreads();
  return fmaxf(fmaxf(buf[0], buf[1]), fmaxf(buf[2], buf[3]));
}

// async global->LDS, 16B per lane; LDS dest = wave-uniform base + lane*16
__device__ __forceinline__ void gl_lds16(const void* g, void* l) {
  __builtin_amdgcn_global_load_lds(
      (const __attribute__((address_space(1))) unsigned int*)g,
      (__attribute__((address_space(3))) unsigned int*)l, 16, 0, 0);
}

__device__ __forceinline__ int q8(float v) {
  return ((int)fminf(fmaxf(rintf(v), -128.0f), 127.0f)) & 0xff;
}

// branch-free erf, Abramowitz-Stegun 7.1.26, |err| <= ~1.5e-7 (poly) + ulps
__device__ __forceinline__ float erf_fast(float x) {
  const float ax = fabsf(x);
  const float t = __builtin_amdgcn_rcpf(fmaf(0.3275911f, ax, 1.0f));
  float p = fmaf(1.061405429f, t, -1.453152027f);
  p = fmaf(p, t, 1.421413741f);
  p = fmaf(p, t, -0.284496736f);
  p = fmaf(p, t, 0.254829592f);
  p = p * t;
  const float e = __expf(-ax * ax);
  const float r = fmaf(-p, e, 1.0f);
  return copysignf(r, x);
}
__device__ __forceinline__ float gelu_fast(float h) {
  return 0.5f * h * (1.0f + erf_fast(h * 0.70710678118654752f));
}

// swizzled fragment address: row stride 128 B, chunk' = chunk ^ (row&7)
__device__ __forceinline__ const i32x4* frag(const char* s, int row, int ckW) {
  return (const i32x4*)&s[row * 128 + ((ckW ^ (row & 7)) << 4)];
}

// ---------- weight scale reduction: sum |w| per group ----------
__global__ __launch_bounds__(256) void wabs_sum_kernel(
    const float4* __restrict__ w, int n_f4, int shift, float* __restrict__ sums) {
  __shared__ float buf[4];
  const int tid = threadIdx.x;
  const int base = blockIdx.x * 4096;
  float acc = 0.0f;
  for (int k = 0; k < 16; ++k) {
    int fi = base + k * 256 + tid;
    if (fi < n_f4) {
      float4 v = w[fi];
      acc += fabsf(v.x) + fabsf(v.y) + fabsf(v.z) + fabsf(v.w);
    }
  }
  acc = block_sum(acc, buf, tid);
  if (tid == 0) atomicAdd(&sums[base >> shift], acc);
}

// ---------- scales ----------
__global__ void mkscales_kernel(const float* __restrict__ wsum, float* __restrict__ sc) {
  if (threadIdx.x == 0) {
    #pragma unroll
    for (int e = 0; e < NE; ++e) {
      float m1 = fmaxf(wsum[e] * (1.0f / 4194304.0f), 1e-5f);
      sc[e] = m1; sc[8 + e] = 1.0f / m1;
      float m2 = fmaxf(wsum[8 + e] * (1.0f / 4194304.0f), 1e-5f);
      sc[16 + e] = m2; sc[24 + e] = 1.0f / m2;
    }
    float mg = fmaxf(wsum[16] * (1.0f / 8192.0f), 1e-5f);
    sc[32] = mg; sc[33] = 1.0f / mg;
  }
}

// ---------- ternary weight quant -> i8 {-1,0,1} ----------
__global__ __launch_bounds__(256) void wquant_kernel(
    const float4* __restrict__ w, int* __restrict__ o, int n_f4, int shift,
    const float* __restrict__ qs) {
  int fi = blockIdx.x * 256 + threadIdx.x;
  if (fi >= n_f4) return;
  const float s = qs[fi >> shift];
  float4 v = w[fi];
  int b0 = ((int)fminf(fmaxf(rintf(v.x * s), -1.0f), 1.0f)) & 0xff;
  int b1 = ((int)fminf(fmaxf(rintf(v.y * s), -1.0f), 1.0f)) & 0xff;
  int b2 = ((int)fminf(fmaxf(rintf(v.z * s), -1.0f), 1.0f)) & 0xff;
  int b3 = ((int)fminf(fmaxf(rintf(v.w * s), -1.0f), 1.0f)) & 0xff;
  o[fi] = b0 | (b1 << 8) | (b2 << 16) | (b3 << 24);
}

// ---------- token preprocess: rmsnorm + act_quant(i8) + gate softmax ----------
__global__ __launch_bounds__(256) void preprocess_kernel(
    const float* __restrict__ x, const float* __restrict__ gw,
    const float* __restrict__ gb, const float* __restrict__ scales,
    int* __restrict__ qx, float* __restrict__ inv_sx, float* __restrict__ gates) {
  __shared__ float buf[4];
  const int t = blockIdx.x, tid = threadIdx.x;
  const float4 xv = ((const float4*)(x + (size_t)t * DIMS))[tid];
  float ss = xv.x * xv.x + xv.y * xv.y + xv.z * xv.z + xv.w * xv.w;
  ss = block_sum(ss, buf, tid);
  const float rr = 32.0f / fmaxf(sqrtf(ss), 1e-12f); // sqrt(1024)=32
  const float y0 = xv.x * rr, y1 = xv.y * rr, y2 = xv.z * rr, y3 = xv.w * rr;
  float am = fmaxf(fmaxf(fabsf(y0), fabsf(y1)), fmaxf(fabsf(y2), fabsf(y3)));
  am = block_max(am, buf, tid);
  const float aclip = fmaxf(am, 1e-5f);
  const float qsc = 127.0f / aclip;
  const float q0 = fminf(fmaxf(rintf(y0 * qsc), -128.0f), 127.0f);
  const float q1 = fminf(fmaxf(rintf(y1 * qsc), -128.0f), 127.0f);
  const float q2 = fminf(fmaxf(rintf(y2 * qsc), -128.0f), 127.0f);
  const float q3 = fminf(fmaxf(rintf(y3 * qsc), -128.0f), 127.0f);
  qx[t * 256 + tid] = (((int)q0) & 0xff) | ((((int)q1) & 0xff) << 8) |
                      ((((int)q2) & 0xff) << 16) | ((((int)q3) & 0xff) << 24);

  const float gsabs = scales[32], gqs = scales[33];
  float lg[NE];
  #pragma unroll
  for (int e = 0; e < NE; ++e) {
    const float4 gv = ((const float4*)(gw + e * DIMS))[tid];
    float t0 = fminf(fmaxf(rintf(gv.x * gqs), -1.0f), 1.0f);
    float t1 = fminf(fmaxf(rintf(gv.y * gqs), -1.0f), 1.0f);
    float t2 = fminf(fmaxf(rintf(gv.z * gqs), -1.0f), 1.0f);
    float t3 = fminf(fmaxf(rintf(gv.w * gqs), -1.0f), 1.0f);
    lg[e] = q0 * t0 + q1 * t1 + q2 * t2 + q3 * t3;
  }
  #pragma unroll
  for (int e = 0; e < NE; ++e) lg[e] = block_sum(lg[e], buf, tid);
  if (tid == 0) {
    const float isx = aclip / 127.0f;
    inv_sx[t] = isx;
    float l[NE], mx = -1e30f;
    #pragma unroll
    for (int e = 0; e < NE; ++e) { l[e] = lg[e] * (isx * gsabs) + gb[e]; mx = fmaxf(mx, l[e]); }
    float s = 0.0f;
    #pragma unroll
    for (int e = 0; e < NE; ++e) { l[e] = expf(l[e] - mx); s += l[e]; }
    const float inv = 1.0f / s;
    #pragma unroll
    for (int e = 0; e < NE; ++e) gates[t * NE + e] = l[e] * inv;
  }
}

// ---------- GEMM1 (i8, 256x128, BK=128): h = qx . w1q * s + b1 -> f16 ----------
__global__ __launch_bounds__(256, 2) void gemm1_kernel(
    const char* __restrict__ qx, const char* __restrict__ w1q,
    const float* __restrict__ scales, const float* __restrict__ inv_sx,
    const float* __restrict__ b1, char* __restrict__ aqa) {
  __shared__ __align__(16) char sA[256 * 128];
  __shared__ __align__(16) char sB[128 * 128];
  const int e = blockIdx.z;
  const char* A = qx;                                   // [T][1024] i8
  const char* Bm = w1q + (size_t)e * HID * DIMS;        // [H][1024] i8
  char* obase = aqa + (size_t)e * T_TOK * ROWB;
  const int n0 = blockIdx.x * 128, m0 = blockIdx.y * 256;
  const int tid = threadIdx.x, lane = tid & 63, wv = tid >> 6;
  const int wr = (wv >> 1) * 128, wc = (wv & 1) * 64, lm = lane & 15, lq = lane >> 4;
  i32x4 acc[8][4] = {};
  for (int k0 = 0; k0 < DIMS; k0 += 128) {
    #pragma unroll
    for (int it = 0; it < 8; ++it) {   // sA: 256 rows x 128 B
      const int c = it * 256 + tid;
      const int row = c >> 3, ckG = (c & 7) ^ (row & 7);
      gl_lds16(A + (size_t)(m0 + row) * DIMS + k0 + ckG * 16, &sA[c * 16]);
    }
    #pragma unroll
    for (int it = 0; it < 4; ++it) {   // sB: 128 rows x 128 B
      const int c = it * 256 + tid;
      const int row = c >> 3, ckG = (c & 7) ^ (row & 7);
      gl_lds16(Bm + (size_t)(n0 + row) * DIMS + k0 + ckG * 16, &sB[c * 16]);
    }
    __syncthreads();
    #pragma unroll
    for (int kk = 0; kk < 2; ++kk) {
      i32x4 av[8], bv[4];
      const int ckW = kk * 4 + lq;
      #pragma unroll
      for (int i = 0; i < 8; ++i) av[i] = *frag(sA, wr + i * 16 + lm, ckW);
      #pragma unroll
      for (int j = 0; j < 4; ++j) bv[j] = *frag(sB, wc + j * 16 + lm, ckW);
      #pragma unroll
      for (int i = 0; i < 8; ++i)
        #pragma unroll
        for (int j = 0; j < 4; ++j)
          acc[i][j] = __builtin_amdgcn_mfma_i32_16x16x64_i8(av[i], bv[j], acc[i][j], 0, 0, 0);
    }
    __syncthreads();
  }
  const float s1 = scales[e];
  float bb[4];
  #pragma unroll
  for (int j = 0; j < 4; ++j) bb[j] = b1[e * HID + n0 + wc + j * 16 + lm];
  #pragma unroll
  for (int i = 0; i < 8; ++i) {
    #pragma unroll
    for (int r = 0; r < 4; ++r) {
      const int row = m0 + wr + i * 16 + lq * 4 + r;
      const float rs = inv_sx[row] * s1;
      _Float16* orow = (_Float16*)(obase + (size_t)row * ROWB);
      #pragma unroll
      for (int j = 0; j < 4; ++j) {
        const int col = n0 + wc + j * 16 + lm;
        orow[col] = (_Float16)fmaf((float)acc[i][j][r], rs, bb[j]);
      }
    }
  }
}

// ---------- per-row GELU + rmsnorm + act_quant: f16 h-row -> i8 in place ----------
__global__ __launch_bounds__(256) void rowquant_kernel(
    char* __restrict__ aqa, float* __restrict__ inv_sa) {
  __shared__ float buf[4];
  const size_t R = blockIdx.x;
  char* rowb = aqa + R * ROWB;
  const int tid = threadIdx.x;
  f16x8 v0 = ((const f16x8*)rowb)[tid * 2];
  f16x8 v1 = ((const f16x8*)rowb)[tid * 2 + 1];
  float f[16];
  #pragma unroll
  for (int k = 0; k < 8; ++k) { f[k] = (float)v0[k]; f[8 + k] = (float)v1[k]; }
  #pragma unroll
  for (int k = 0; k < 16; ++k) f[k] = gelu_fast(f[k]);   // GELU lives here (mem-bound kernel)
  float ss = 0.0f;
  #pragma unroll
  for (int k = 0; k < 16; ++k) ss += f[k] * f[k];
  ss = block_sum(ss, buf, tid);           // barrier: reads complete before writes below
  const float rr = 64.0f / fmaxf(sqrtf(ss), 1e-12f); // sqrt(4096)=64
  float am = 0.0f;
  #pragma unroll
  for (int k = 0; k < 16; ++k) am = fmaxf(am, fabsf(f[k] * rr));
  am = block_max(am, buf, tid);
  const float aclip = fmaxf(am, 1e-5f);
  const float qsc = rr * 127.0f / aclip;
  int4 o;
  o.x = q8(f[0] * qsc) | (q8(f[1] * qsc) << 8) | (q8(f[2] * qsc) << 16) | (q8(f[3] * qsc) << 24);
  o.y = q8(f[4] * qsc) | (q8(f[5] * qsc) << 8) | (q8(f[6] * qsc) << 16) | (q8(f[7] * qsc) << 24);
  o.z = q8(f[8] * qsc) | (q8(f[9] * qsc) << 8) | (q8(f[10] * qsc) << 16) | (q8(f[11] * qsc) << 24);
  o.w = q8(f[12] * qsc) | (q8(f[13] * qsc) << 8) | (q8(f[14] * qsc) << 16) | (q8(f[15] * qsc) << 24);
  ((int4*)rowb)[tid] = o;
  if (tid == 0) inv_sa[R] = aclip / 127.0f;
}

// ---------- GEMM2 (i8, 256x128, BK=128): eout(f16) = gate*(qa.w2q*scale + b2) ----------
__global__ __launch_bounds__(256, 2) void gemm2_kernel(
    const char* __restrict__ aqa, const char* __restrict__ w2q,
    const float* __restrict__ scales, const float* __restrict__ inv_sa,
    const float* __restrict__ b2, const float* __restrict__ gates,
    void* __restrict__ dstv, int use_atomic) {
  __shared__ __align__(16) char sA[256 * 128];
  __shared__ __align__(16) char sB[128 * 128];
  const int e = blockIdx.z;
  const char* A = aqa + (size_t)e * T_TOK * ROWB;        // [T] rows, i8 in first 4096 B
  const char* Bm = w2q + (size_t)e * DIMS * HID;         // [D][4096] i8
  const int n0 = blockIdx.x * 128, m0 = blockIdx.y * 256;
  const int tid = threadIdx.x, lane = tid & 63, wv = tid >> 6;
  const int wr = (wv >> 1) * 128, wc = (wv & 1) * 64, lm = lane & 15, lq = lane >> 4;
  i32x4 acc[8][4] = {};
  for (int k0 = 0; k0 < HID; k0 += 128) {
    #pragma unroll
    for (int it = 0; it < 8; ++it) {
      const int c = it * 256 + tid;
      const int row = c >> 3, ckG = (c & 7) ^ (row & 7);
      gl_lds16(A + (size_t)(m0 + row) * ROWB + k0 + ckG * 16, &sA[c * 16]);
    }
    #pragma unroll
    for (int it = 0; it < 4; ++it) {
      const int c = it * 256 + tid;
      const int row = c >> 3, ckG = (c & 7) ^ (row & 7);
      gl_lds16(Bm + (size_t)(n0 + row) * HID + k0 + ckG * 16, &sB[c * 16]);
    }
    __syncthreads();
    #pragma unroll
    for (int kk = 0; kk < 2; ++kk) {
      i32x4 av[8], bv[4];
      const int ckW = kk * 4 + lq;
      #pragma unroll
      for (int i = 0; i < 8; ++i) av[i] = *frag(sA, wr + i * 16 + lm, ckW);
      #pragma unroll
      for (int j = 0; j < 4; ++j) bv[j] = *frag(sB, wc + j * 16 + lm, ckW);
      #pragma unroll
      for (int i = 0; i < 8; ++i)
        #pragma unroll
        for (int j = 0; j < 4; ++j)
          acc[i][j] = __builtin_amdgcn_mfma_i32_16x16x64_i8(av[i], bv[j], acc[i][j], 0, 0, 0);
    }
    __syncthreads();
  }
  const float s2 = scales[16 + e];
  float bb[4];
  #pragma unroll
  for (int j = 0; j < 4; ++j) bb[j] = b2[e * DIMS + n0 + wc + j * 16 + lm];
  #pragma unroll
  for (int i = 0; i < 8; ++i) {
    #pragma unroll
    for (int r = 0; r < 4; ++r) {
      const int row = m0 + wr + i * 16 + lq * 4 + r;
      const float rs = inv_sa[(size_t)e * T_TOK + row] * s2;
      const float g = gates[row * NE + e];
      #pragma unroll
      for (int j = 0; j < 4; ++j) {
        const int col = n0 + wc + j * 16 + lm;
        const float v = g * fmaf((float)acc[i][j][r], rs, bb[j]);
        if (use_atomic) atomicAdd(&((float*)dstv)[(size_t)row * DIMS + col], v);
        else ((_Float16*)dstv)[((size_t)e * T_TOK + row) * DIMS + col] = (_Float16)v;
      }
    }
  }
}

// ---------- expert-sum reduce: f16 eout -> f32 out ----------
__global__ __launch_bounds__(256) void reduce_kernel(
    const f16x8* __restrict__ eout, float4* __restrict__ out) {
  const int i = blockIdx.x * 256 + threadIdx.x;  // over T*D/8 = 524288
  float s[8] = {};
  #pragma unroll
  for (int e = 0; e < NE; ++e) {
    f16x8 v = eout[(size_t)e * (T_TOK * DIMS / 8) + i];
    #pragma unroll
    for (int k = 0; k < 8; ++k) s[k] += (float)v[k];
  }
  float4 o0; o0.x = s[0]; o0.y = s[1]; o0.z = s[2]; o0.w = s[3];
  float4 o1; o1.x = s[4]; o1.y = s[5]; o1.z = s[6]; o1.w = s[7];
  out[i * 2]     = o0;
  out[i * 2 + 1] = o1;
}

// ---------- host orchestration ----------
extern "C" void kernel_launch(void* const* d_in, const int* in_sizes, int n_in,
                              void* d_out, int out_size, void* d_ws, size_t ws_size,
                              hipStream_t stream) {
  const float* x  = (const float*)d_in[0];
  const float* gw = (const float*)d_in[1];
  const float* gb = (const float*)d_in[2];
  const float* w1 = (const float*)d_in[3];
  const float* b1 = (const float*)d_in[4];
  const float* w2 = (const float*)d_in[5];
  const float* b2 = (const float*)d_in[6];
  float* outp = (float*)d_out;
  char* ws = (char*)d_ws;

  float* wsum   = (float*)(ws + 0);        // 17 floats
  float* scales = (float*)(ws + 256);      // 34 floats
  float* inv_sx = (float*)(ws + 4096);     // 4096 floats
  float* gates  = (float*)(ws + 20480);    // 32768 floats
  float* inv_sa = (float*)(ws + 151552);   // 32768 floats
  char*  qx     = ws + 282624;             // 4 MiB i8 [T][1024]
  char*  w1q    = ws + 4476928;            // 32 MiB i8
  char*  w2q    = ws + 38031360;           // 32 MiB i8
  char*  aqa    = ws + 71585792;           // 256 MiB: [E*T] rows of 8192 B
  char*  eout   = ws + 340021248;          // 64 MiB f16 [E][T][D] (optional)

  const bool has_eout = ws_size >= 340021248ull + 67108864ull;

  hipMemsetAsync(wsum, 0, 17 * sizeof(float), stream);
  wabs_sum_kernel<<<2048, 256, 0, stream>>>((const float4*)w1, 8388608, 20, wsum + 0);
  wabs_sum_kernel<<<2048, 256, 0, stream>>>((const float4*)w2, 8388608, 20, wsum + 8);
  wabs_sum_kernel<<<1,    256, 0, stream>>>((const float4*)gw, 2048,    30, wsum + 16);
  mkscales_kernel<<<1, 64, 0, stream>>>(wsum, scales);
  wquant_kernel<<<32768, 256, 0, stream>>>((const float4*)w1, (int*)w1q, 8388608, 20, scales + 8);
  wquant_kernel<<<32768, 256, 0, stream>>>((const float4*)w2, (int*)w2q, 8388608, 20, scales + 24);
  preprocess_kernel<<<4096, 256, 0, stream>>>(x, gw, gb, scales, (int*)qx, inv_sx, gates);

  gemm1_kernel<<<dim3(32, 16, 8), 256, 0, stream>>>(qx, w1q, scales, inv_sx, b1, aqa);
  rowquant_kernel<<<32768, 256, 0, stream>>>(aqa, inv_sa);

  if (has_eout) {
    gemm2_kernel<<<dim3(8, 16, 8), 256, 0, stream>>>(
        aqa, w2q, scales, inv_sa, b2, gates, eout, 0);
    reduce_kernel<<<2048, 256, 0, stream>>>((const f16x8*)eout, (float4*)outp);
  } else {
    hipMemsetAsync(outp, 0, (size_t)out_size * sizeof(float), stream);
    gemm2_kernel<<<dim3(8, 16, 8), 256, 0, stream>>>(
        aqa, w2q, scales, inv_sa, b2, gates, outp, 1);
  }
}